// Round 8
// baseline (201.735 us; speedup 1.0000x reference)
//
#include <hip/hip_runtime.h>
#include <hip/hip_fp16.h>

#define NN 100000
#define NE 1600000

// Radix partition params: buckets of 256 nodes
#define K_B 391                          // ceil(NN/256) buckets
#define B_P 256                          // partition blocks
#define CH  ((NE + B_P - 1) / B_P)       // 6250 edges per partition block
#define NSC (K_B * B_P)                  // histogram table size (100096)
#define NBLK_H ((NSC + 1023) / 1024)     // 98 blocks for hist scan
#define L2_GRID 2048                     // persistent blocks for k_layer2

// ---------------------------------------------------------------------------
// edge_index dtype detection: if int64 (values < 2^31), odd 32-bit words are 0.
__global__ void k_detect(const unsigned int* w, int* flag) {
    int i = blockIdx.x * blockDim.x + threadIdx.x;
    if (i < 65536 && w[2 * i + 1] != 0u) *flag = 1;
}

__device__ __forceinline__ void load_edge(const void* ei, int is32, int e,
                                          int& s, int& d) {
    if (is32) {
        const int* p = (const int*)ei;
        s = p[e]; d = p[NE + e];
    } else {
        const long long* p = (const long long*)ei;
        s = (int)p[e]; d = (int)p[NE + e];
    }
}

// ---------------------------------------------------------------------------
// P1: per-block histogram of dst>>8 over this block's edge chunk
__global__ __launch_bounds__(256) void k_hist(const void* ei, const int* __restrict__ flag,
                                              int* __restrict__ hist) {
    __shared__ int h[K_B];
    for (int i = threadIdx.x; i < K_B; i += 256) h[i] = 0;
    __syncthreads();
    int b = blockIdx.x;
    int is32 = *flag;
    int e0 = b * CH, e1 = min(e0 + CH, NE);
    for (int e = e0 + threadIdx.x; e < e1; e += 256) {
        int d = is32 ? ((const int*)ei)[NE + e] : (int)((const long long*)ei)[NE + e];
        atomicAdd(&h[d >> 8], 1);
    }
    __syncthreads();
    for (int i = threadIdx.x; i < K_B; i += 256) hist[i * B_P + b] = h[i];
}

// ---------------------------------------------------------------------------
// Generalized hierarchical exclusive scan (3 kernels), n <= 128*1024
__global__ __launch_bounds__(256) void k_gscan1(const int* __restrict__ in,
                                                int* __restrict__ ex,
                                                int* __restrict__ bsum, int n) {
    __shared__ int lds[256];
    int b = blockIdx.x, t = threadIdx.x;
    int base = b * 1024 + t * 4;
    int v[4];
#pragma unroll
    for (int k = 0; k < 4; ++k) { int i = base + k; v[k] = (i < n) ? in[i] : 0; }
    int s = v[0] + v[1] + v[2] + v[3];
    lds[t] = s;
    __syncthreads();
    for (int off = 1; off < 256; off <<= 1) {
        int tmp = (t >= off) ? lds[t - off] : 0;
        __syncthreads();
        lds[t] += tmp;
        __syncthreads();
    }
    int run = lds[t] - s;
#pragma unroll
    for (int k = 0; k < 4; ++k) {
        int i = base + k;
        if (i < n) ex[i] = run;
        run += v[k];
    }
    if (t == 255) bsum[b] = lds[255];
}

__global__ __launch_bounds__(128) void k_gscan2(int* bsum, int nblk) {
    __shared__ int lds[128];
    int t = threadIdx.x;
    int v = (t < nblk) ? bsum[t] : 0;
    lds[t] = v;
    __syncthreads();
    for (int off = 1; off < 128; off <<= 1) {
        int tmp = (t >= off) ? lds[t - off] : 0;
        __syncthreads();
        lds[t] += tmp;
        __syncthreads();
    }
    if (t < nblk) bsum[t] = lds[t] - v;  // exclusive
}

__global__ void k_gscan3(int* __restrict__ ex, const int* __restrict__ bsum, int n) {
    int i = blockIdx.x * blockDim.x + threadIdx.x;
    if (i < n) ex[i] += bsum[i >> 10];
}

// ---------------------------------------------------------------------------
// P3: partition edges into per-(block,bucket) contiguous runs (LDS cursors only)
__global__ __launch_bounds__(256) void k_part(const void* ei, const int* __restrict__ flag,
                                              const int* __restrict__ off,
                                              unsigned* __restrict__ packed) {
    __shared__ int cur[K_B];
    int b = blockIdx.x;
    for (int i = threadIdx.x; i < K_B; i += 256) cur[i] = off[i * B_P + b];
    __syncthreads();
    int is32 = *flag;
    int e0 = b * CH, e1 = min(e0 + CH, NE);
    for (int e = e0 + threadIdx.x; e < e1; e += 256) {
        int s, d;
        load_edge(ei, is32, e, s, d);
        int k = d >> 8;
        int pos = atomicAdd(&cur[k], 1);
        packed[pos] = ((unsigned)s << 8) | (unsigned)(d & 255);
    }
}

// ---------------------------------------------------------------------------
// P4 fused per-bucket: count -> local scan -> rowptr/dinv/xn -> place ssrc.
__global__ __launch_bounds__(256) void k_bucket(const int* __restrict__ off,
                                                const unsigned* __restrict__ packed,
                                                const float* __restrict__ x,
                                                int* __restrict__ rowptr,
                                                float* __restrict__ dinv,
                                                float2* __restrict__ xn,
                                                int* __restrict__ ssrc) {
    __shared__ int cnt[256];
    __shared__ int excl[256];
    int k = blockIdx.x, t = threadIdx.x;
    cnt[t] = 0;
    __syncthreads();
    int g0 = off[k * B_P];
    int g1 = (k == K_B - 1) ? NE : off[(k + 1) * B_P];
    for (int i = g0 + t; i < g1; i += 256)
        atomicAdd(&cnt[packed[i] & 255u], 1);
    __syncthreads();
    int v = cnt[t];
    excl[t] = v;
    __syncthreads();
    for (int o = 1; o < 256; o <<= 1) {
        int tmp = (t >= o) ? excl[t - o] : 0;
        __syncthreads();
        excl[t] += tmp;
        __syncthreads();
    }
    int rb = g0 + excl[t] - v;  // rowptr[n]: bucket start + local exclusive prefix
    int n = (k << 8) + t;
    if (n < NN) {
        rowptr[n] = rb;
        float di = rsqrtf((float)(v + 1));  // +1 self-loop
        dinv[n] = di;
        float2 xv = ((const float2*)x)[n];
        xn[n] = make_float2(xv.x * di, xv.y * di);
    }
    if (k == K_B - 1 && t == 0) rowptr[NN] = NE;
    __syncthreads();
    excl[t] = rb;   // reuse as row base for placement
    cnt[t] = 0;
    __syncthreads();
    for (int i = g0 + t; i < g1; i += 256) {
        unsigned pk = packed[i];
        int dl = pk & 255u;
        int r = atomicAdd(&cnt[dl], 1);
        ssrc[excl[dl] + r] = (int)(pk >> 8);
    }
}

// ---------------------------------------------------------------------------
// Layer 1 fused: lane-parallel agg of xn (2-wide) + 2->64 transform + bias +
// ReLU + next-layer dinv scale.  hn1[n][j] = fp16( dinv[n]*relu(...) )
__global__ __launch_bounds__(256) void k_layer1(const int* __restrict__ rowptr,
                                                const int* __restrict__ ssrc,
                                                const float2* __restrict__ xn,
                                                const float* __restrict__ dinv,
                                                const float* __restrict__ W1,
                                                const float* __restrict__ b1,
                                                __half* __restrict__ hn1) {
    int node = blockIdx.x * 4 + (threadIdx.x >> 6);
    if (node >= NN) return;
    int lane = threadIdx.x & 63;
    int s0 = rowptr[node], e0 = rowptr[node + 1];
    float ax = 0.f, ay = 0.f;
    for (int i = s0 + lane; i < e0; i += 64) {
        float2 v = xn[ssrc[i]];
        ax += v.x; ay += v.y;
    }
#pragma unroll
    for (int m = 1; m < 64; m <<= 1) {
        ax += __shfl_xor(ax, m, 64);
        ay += __shfl_xor(ay, m, 64);
    }
    float2 a = xn[node];  // self loop
    ax += a.x; ay += a.y;
    float di = dinv[node];
    ax *= di; ay *= di;
    float v = fmaf(ax, W1[lane], fmaf(ay, W1[64 + lane], b1[lane]));
    hn1[(size_t)node * 64 + lane] = __float2half(di * fmaxf(v, 0.f));
}

// ---------------------------------------------------------------------------
// Layer 2+3a fused, persistent blocks: half2 dual-edge gather (lanes 0-31 take
// even edge, 32-63 odd edge; lane l covers features 2l,2l+1), combine via
// shfl_xor(32), 64x64 GEMM from LDS W2, bias+ReLU+dinv, dot W3 -> t3.
__global__ __launch_bounds__(256) void k_layer2(const int* __restrict__ rowptr,
                                                const int* __restrict__ ssrc,
                                                const __half* __restrict__ hn1,
                                                const float* __restrict__ dinv,
                                                const float* __restrict__ W2,
                                                const float* __restrict__ b2,
                                                const float* __restrict__ W3,
                                                float* __restrict__ t3) {
    __shared__ float Ws[64 * 64];
    __shared__ float gs[4][64];
    for (int i = threadIdx.x; i < 64 * 64; i += 256) Ws[i] = W2[i];
    __syncthreads();
    const __half2* hp = (const __half2*)hn1;   // 32 half2 per node row
    int w = threadIdx.x >> 6, lane = threadIdx.x & 63;
    int half = lane >> 5;       // 0: even edges, 1: odd edges
    int l5 = lane & 31;         // feature pair index
    float w3 = W3[lane];
    float bias = b2[lane];
    for (int node = blockIdx.x * 4 + w; node < NN; node += L2_GRID * 4) {
        int start = rowptr[node], end = rowptr[node + 1];
        float sx = 0.f, sy = 0.f;
        int i = start;
        for (; i + 4 <= end; i += 4) {   // 4 edges per iter, 2 loads in flight
            int sA = ssrc[i + half];
            int sB = ssrc[i + 2 + half];
            float2 fA = __half22float2(hp[((unsigned)sA << 5) + l5]);
            float2 fB = __half22float2(hp[((unsigned)sB << 5) + l5]);
            sx += fA.x + fB.x;
            sy += fA.y + fB.y;
        }
        for (; i + 2 <= end; i += 2) {
            int s = ssrc[i + half];
            float2 f = __half22float2(hp[((unsigned)s << 5) + l5]);
            sx += f.x; sy += f.y;
        }
        if (i < end && half == 0) {      // odd tail edge: lower half only
            float2 f = __half22float2(hp[((unsigned)ssrc[i] << 5) + l5]);
            sx += f.x; sy += f.y;
        }
        // merge even/odd halves
        sx += __shfl_xor(sx, 32, 64);
        sy += __shfl_xor(sy, 32, 64);
        // self loop
        float2 fs = __half22float2(hp[((unsigned)node << 5) + l5]);
        sx += fs.x; sy += fs.y;
        // publish aggregated row (features 2*l5, 2*l5+1)
        if (half == 0) {
            gs[w][2 * l5]     = sx;
            gs[w][2 * l5 + 1] = sy;
        }
        float o = 0.f;
#pragma unroll
        for (int k = 0; k < 64; ++k) o = fmaf(gs[w][k], Ws[k * 64 + lane], o);
        float di = dinv[node];
        float v = fmaf(di, o, bias);
        float r = di * fmaxf(v, 0.f) * w3;   // hn2 element * W3, then reduce
#pragma unroll
        for (int m = 1; m < 64; m <<= 1) r += __shfl_xor(r, m, 64);
        if (lane == 0) t3[node] = r;
    }
}

// Scalar last layer: out[n] = dinv[n]*(t3[n] + sum t3[src]) + b3
__global__ void k_aggregate3(const int* __restrict__ rowptr, const int* __restrict__ ssrc,
                             const float* __restrict__ t3, const float* __restrict__ dinv,
                             const float* __restrict__ b3, float* __restrict__ out) {
    int n = blockIdx.x * blockDim.x + threadIdx.x;
    if (n >= NN) return;
    int s = rowptr[n], e = rowptr[n + 1];
    float acc = t3[n];
    int i = s;
    for (; i + 4 <= e; i += 4)
        acc += t3[ssrc[i]] + t3[ssrc[i + 1]] + t3[ssrc[i + 2]] + t3[ssrc[i + 3]];
    for (; i < e; ++i) acc += t3[ssrc[i]];
    out[n] = dinv[n] * acc + b3[0];
}

// ---------------------------------------------------------------------------
extern "C" void kernel_launch(void* const* d_in, const int* in_sizes, int n_in,
                              void* d_out, int out_size, void* d_ws, size_t ws_size,
                              hipStream_t stream) {
    const float* x  = (const float*)d_in[0];
    const void*  ei = d_in[1];
    const float* W1 = (const float*)d_in[2];
    const float* b1 = (const float*)d_in[3];
    const float* W2 = (const float*)d_in[4];
    const float* b2 = (const float*)d_in[5];
    const float* W3 = (const float*)d_in[6];
    const float* b3 = (const float*)d_in[7];
    float* out = (float*)d_out;

    char* ws = (char*)d_ws;
    size_t off_b = 0;
    auto take = [&](size_t bytes) -> char* {
        char* p = ws + off_b;
        off_b = (off_b + bytes + 255) & ~(size_t)255;
        return p;
    };
    float*    dinv   = (float*)take((size_t)NN * 4);
    int*      flag   = (int*)take(4);
    int*      bsum   = (int*)take(128 * 4);
    int*      rowptr = (int*)take((size_t)(NN + 1) * 4);
    int*      hist   = (int*)take((size_t)NSC * 4);
    int*      histS  = (int*)take((size_t)NSC * 4);
    unsigned* packed = (unsigned*)take((size_t)NE * 4);
    int*      ssrc   = (int*)take((size_t)NE * 4);
    float2*   xn     = (float2*)take((size_t)NN * 8);
    __half*   hn1    = (__half*)take((size_t)NN * 64 * 2);
    float*    t3     = (float*)take((size_t)NN * 4);

    // --- edge dtype detect ---
    hipMemsetAsync(flag, 0, 4, stream);
    k_detect<<<256, 256, 0, stream>>>((const unsigned int*)ei, flag);

    // --- atomic-free radix partition by dst (coarse buckets of 256 nodes) ---
    k_hist<<<B_P, 256, 0, stream>>>(ei, flag, hist);
    k_gscan1<<<NBLK_H, 256, 0, stream>>>(hist, histS, bsum, NSC);
    k_gscan2<<<1, 128, 0, stream>>>(bsum, NBLK_H);
    k_gscan3<<<(NSC + 255) / 256, 256, 0, stream>>>(histS, bsum, NSC);
    k_part<<<B_P, 256, 0, stream>>>(ei, flag, histS, packed);

    // --- fused per-bucket: count + scan -> rowptr/dinv/xn + place ssrc ---
    k_bucket<<<K_B, 256, 0, stream>>>(histS, packed, x, rowptr, dinv, xn, ssrc);

    const int nblk_agg = (NN + 3) / 4;  // 4 waves (nodes) per block

    // --- layer 1 (lane-parallel 2-wide aggregate + transform, fp16 out) ---
    k_layer1<<<nblk_agg, 256, 0, stream>>>(rowptr, ssrc, xn, dinv, W1, b1, hn1);

    // --- layer 2 + 3a (persistent, half2 dual-edge gather + GEMM + W3 dot) ---
    k_layer2<<<L2_GRID, 256, 0, stream>>>(rowptr, ssrc, hn1, dinv, W2, b2, W3, t3);

    // --- layer 3b (scalar aggregate) ---
    k_aggregate3<<<(NN + 255) / 256, 256, 0, stream>>>(rowptr, ssrc, t3, dinv, b3, out);
}

// Round 11
// 185.075 us; speedup vs baseline: 1.0900x; 1.0900x over previous
//
#include <hip/hip_runtime.h>
#include <hip/hip_fp16.h>

#define NN 100000
#define NE 1600000

// Radix partition params: buckets of 256 nodes
#define K_B 391                          // ceil(NN/256) buckets
#define B_P 256                          // partition blocks
#define CH  ((NE + B_P - 1) / B_P)       // 6250 edges per partition block
#define NSC (K_B * B_P)                  // histogram table size (100096)
#define NBLK_H ((NSC + 1023) / 1024)     // 98 blocks for hist scan

// ---------------------------------------------------------------------------
// edge_index dtype detection: if int64 (values < 2^31), odd 32-bit words are 0.
__global__ void k_detect(const unsigned int* w, int* flag) {
    int i = blockIdx.x * blockDim.x + threadIdx.x;
    if (i < 65536 && w[2 * i + 1] != 0u) *flag = 1;
}

__device__ __forceinline__ void load_edge(const void* ei, int is32, int e,
                                          int& s, int& d) {
    if (is32) {
        const int* p = (const int*)ei;
        s = p[e]; d = p[NE + e];
    } else {
        const long long* p = (const long long*)ei;
        s = (int)p[e]; d = (int)p[NE + e];
    }
}

// ---------------------------------------------------------------------------
// P1: per-block histogram of dst>>8 over this block's edge chunk
__global__ __launch_bounds__(256) void k_hist(const void* ei, const int* __restrict__ flag,
                                              int* __restrict__ hist) {
    __shared__ int h[K_B];
    for (int i = threadIdx.x; i < K_B; i += 256) h[i] = 0;
    __syncthreads();
    int b = blockIdx.x;
    int is32 = *flag;
    int e0 = b * CH, e1 = min(e0 + CH, NE);
    for (int e = e0 + threadIdx.x; e < e1; e += 256) {
        int d = is32 ? ((const int*)ei)[NE + e] : (int)((const long long*)ei)[NE + e];
        atomicAdd(&h[d >> 8], 1);
    }
    __syncthreads();
    for (int i = threadIdx.x; i < K_B; i += 256) hist[i * B_P + b] = h[i];
}

// ---------------------------------------------------------------------------
// Generalized hierarchical exclusive scan (3 kernels), n <= 128*1024
__global__ __launch_bounds__(256) void k_gscan1(const int* __restrict__ in,
                                                int* __restrict__ ex,
                                                int* __restrict__ bsum, int n) {
    __shared__ int lds[256];
    int b = blockIdx.x, t = threadIdx.x;
    int base = b * 1024 + t * 4;
    int v[4];
#pragma unroll
    for (int k = 0; k < 4; ++k) { int i = base + k; v[k] = (i < n) ? in[i] : 0; }
    int s = v[0] + v[1] + v[2] + v[3];
    lds[t] = s;
    __syncthreads();
    for (int off = 1; off < 256; off <<= 1) {
        int tmp = (t >= off) ? lds[t - off] : 0;
        __syncthreads();
        lds[t] += tmp;
        __syncthreads();
    }
    int run = lds[t] - s;
#pragma unroll
    for (int k = 0; k < 4; ++k) {
        int i = base + k;
        if (i < n) ex[i] = run;
        run += v[k];
    }
    if (t == 255) bsum[b] = lds[255];
}

__global__ __launch_bounds__(128) void k_gscan2(int* bsum, int nblk) {
    __shared__ int lds[128];
    int t = threadIdx.x;
    int v = (t < nblk) ? bsum[t] : 0;
    lds[t] = v;
    __syncthreads();
    for (int off = 1; off < 128; off <<= 1) {
        int tmp = (t >= off) ? lds[t - off] : 0;
        __syncthreads();
        lds[t] += tmp;
        __syncthreads();
    }
    if (t < nblk) bsum[t] = lds[t] - v;  // exclusive
}

__global__ void k_gscan3(int* __restrict__ ex, const int* __restrict__ bsum, int n) {
    int i = blockIdx.x * blockDim.x + threadIdx.x;
    if (i < n) ex[i] += bsum[i >> 10];
}

// ---------------------------------------------------------------------------
// P3: partition edges into per-(block,bucket) contiguous runs (LDS cursors only)
__global__ __launch_bounds__(256) void k_part(const void* ei, const int* __restrict__ flag,
                                              const int* __restrict__ off,
                                              unsigned* __restrict__ packed) {
    __shared__ int cur[K_B];
    int b = blockIdx.x;
    for (int i = threadIdx.x; i < K_B; i += 256) cur[i] = off[i * B_P + b];
    __syncthreads();
    int is32 = *flag;
    int e0 = b * CH, e1 = min(e0 + CH, NE);
    for (int e = e0 + threadIdx.x; e < e1; e += 256) {
        int s, d;
        load_edge(ei, is32, e, s, d);
        int k = d >> 8;
        int pos = atomicAdd(&cur[k], 1);
        packed[pos] = ((unsigned)s << 8) | (unsigned)(d & 255);
    }
}

// ---------------------------------------------------------------------------
// P4 fused per-bucket: count -> local scan -> rowptr/dinv/xn -> place ssrc.
__global__ __launch_bounds__(256) void k_bucket(const int* __restrict__ off,
                                                const unsigned* __restrict__ packed,
                                                const float* __restrict__ x,
                                                int* __restrict__ rowptr,
                                                float* __restrict__ dinv,
                                                float2* __restrict__ xn,
                                                int* __restrict__ ssrc) {
    __shared__ int cnt[256];
    __shared__ int excl[256];
    int k = blockIdx.x, t = threadIdx.x;
    cnt[t] = 0;
    __syncthreads();
    int g0 = off[k * B_P];
    int g1 = (k == K_B - 1) ? NE : off[(k + 1) * B_P];
    for (int i = g0 + t; i < g1; i += 256)
        atomicAdd(&cnt[packed[i] & 255u], 1);
    __syncthreads();
    int v = cnt[t];
    excl[t] = v;
    __syncthreads();
    for (int o = 1; o < 256; o <<= 1) {
        int tmp = (t >= o) ? excl[t - o] : 0;
        __syncthreads();
        excl[t] += tmp;
        __syncthreads();
    }
    int rb = g0 + excl[t] - v;  // rowptr[n]: bucket start + local exclusive prefix
    int n = (k << 8) + t;
    if (n < NN) {
        rowptr[n] = rb;
        float di = rsqrtf((float)(v + 1));  // +1 self-loop
        dinv[n] = di;
        float2 xv = ((const float2*)x)[n];
        xn[n] = make_float2(xv.x * di, xv.y * di);
    }
    if (k == K_B - 1 && t == 0) rowptr[NN] = NE;
    __syncthreads();
    excl[t] = rb;   // reuse as row base for placement
    cnt[t] = 0;
    __syncthreads();
    for (int i = g0 + t; i < g1; i += 256) {
        unsigned pk = packed[i];
        int dl = pk & 255u;
        int r = atomicAdd(&cnt[dl], 1);
        ssrc[excl[dl] + r] = (int)(pk >> 8);
    }
}

// ---------------------------------------------------------------------------
// Layer 1 fused: lane-parallel agg of xn (2-wide) + 2->64 transform + bias +
// ReLU + next-layer dinv scale.  hn1[n][j] = fp16( dinv[n]*relu(...) )
__global__ __launch_bounds__(256) void k_layer1(const int* __restrict__ rowptr,
                                                const int* __restrict__ ssrc,
                                                const float2* __restrict__ xn,
                                                const float* __restrict__ dinv,
                                                const float* __restrict__ W1,
                                                const float* __restrict__ b1,
                                                __half* __restrict__ hn1) {
    int node = blockIdx.x * 4 + (threadIdx.x >> 6);
    if (node >= NN) return;
    int lane = threadIdx.x & 63;
    int s0 = rowptr[node], e0 = rowptr[node + 1];
    float ax = 0.f, ay = 0.f;
    for (int i = s0 + lane; i < e0; i += 64) {
        float2 v = xn[ssrc[i]];
        ax += v.x; ay += v.y;
    }
#pragma unroll
    for (int m = 1; m < 64; m <<= 1) {
        ax += __shfl_xor(ax, m, 64);
        ay += __shfl_xor(ay, m, 64);
    }
    float2 a = xn[node];  // self loop
    ax += a.x; ay += a.y;
    float di = dinv[node];
    ax *= di; ay *= di;
    float v = fmaf(ax, W1[lane], fmaf(ay, W1[64 + lane], b1[lane]));
    hn1[(size_t)node * 64 + lane] = __float2half(di * fmaxf(v, 0.f));
}

// ---------------------------------------------------------------------------
// Layer 2+3a fused: wide-gather aggregate of hn1 + 64x64 GEMM (W2 in LDS) +
// bias + ReLU + dinv scale + dot with W3 -> t3[n].
// Gather: lane (g,fb)=(lane>>3,lane&7); 8 lanes cover one edge row via
// float4 (8 fp16), one instr = 8 edges = 1KB. Edge indices pre-loaded 64 at
// a time (one coalesced load) and distributed by shfl (all lanes execute the
// shfl; only the load is predicated — r10 fix).
// FIX vs r10: the gs publish is exec-masked (lanes g==0 only); a block-wide
// __syncthreads() between publish and the GEMM read makes the LDS
// write->read ordering airtight (race showed as post-timing divergence with
// stale-LDS-magnitude errors). Every thread reaches the barrier exactly once.
__global__ __launch_bounds__(256) void k_layer2(const int* __restrict__ rowptr,
                                                const int* __restrict__ ssrc,
                                                const __half* __restrict__ hn1,
                                                const float* __restrict__ dinv,
                                                const float* __restrict__ W2,
                                                const float* __restrict__ b2,
                                                const float* __restrict__ W3,
                                                float* __restrict__ t3) {
    __shared__ float Ws[64 * 64];
    __shared__ float gs[4][64];
    for (int i = threadIdx.x; i < 64 * 64; i += 256) Ws[i] = W2[i];
    __syncthreads();
    int node = blockIdx.x * 4 + (threadIdx.x >> 6);   // NN = 4*25000: always < NN
    int w = threadIdx.x >> 6, lane = threadIdx.x & 63;
    int g = lane >> 3, fb = lane & 7;
    const float4* hp4 = (const float4*)hn1;   // 8 float4 per node row
    int start = rowptr[node];
    int m = rowptr[node + 1] - start;
    int cnt = m + 1;                          // edges + self row
    float a0=0.f,a1=0.f,a2=0.f,a3=0.f,a4=0.f,a5=0.f,a6=0.f,a7=0.f;
    for (int c0 = 0; c0 < cnt; c0 += 64) {
        int j = c0 + lane;
        int sreg = (j < m) ? ssrc[start + j] : node;  // j==m -> self row
        int lim = min(cnt - c0, 64);                  // wave-uniform
        for (int base = 0; base < lim; base += 8) {
            int s = __shfl(sreg, base + g, 64);       // ALL lanes participate
            if (base + g < lim) {
                float4 raw = hp4[(size_t)(unsigned)s * 8 + fb];
                const __half2* hh = (const __half2*)&raw;
                float2 f0 = __half22float2(hh[0]);
                float2 f1 = __half22float2(hh[1]);
                float2 f2 = __half22float2(hh[2]);
                float2 f3 = __half22float2(hh[3]);
                a0 += f0.x; a1 += f0.y; a2 += f1.x; a3 += f1.y;
                a4 += f2.x; a5 += f2.y; a6 += f3.x; a7 += f3.y;
            }
        }
    }
    // reduce across the 8 edge-groups (lanes sharing fb)
#pragma unroll
    for (int mask = 8; mask < 64; mask <<= 1) {
        a0 += __shfl_xor(a0, mask, 64);
        a1 += __shfl_xor(a1, mask, 64);
        a2 += __shfl_xor(a2, mask, 64);
        a3 += __shfl_xor(a3, mask, 64);
        a4 += __shfl_xor(a4, mask, 64);
        a5 += __shfl_xor(a5, mask, 64);
        a6 += __shfl_xor(a6, mask, 64);
        a7 += __shfl_xor(a7, mask, 64);
    }
    if (g == 0) {   // lanes 0..7 publish features fb*8 .. fb*8+7
        float* gw = &gs[w][fb * 8];
        gw[0]=a0; gw[1]=a1; gw[2]=a2; gw[3]=a3;
        gw[4]=a4; gw[5]=a5; gw[6]=a6; gw[7]=a7;
    }
    __syncthreads();   // guarantee publish lands before any lane's GEMM read
    float o = 0.f;
#pragma unroll
    for (int k = 0; k < 64; ++k) o = fmaf(gs[w][k], Ws[k * 64 + lane], o);
    float di = dinv[node];
    float v = fmaf(di, o, b2[lane]);
    float r = di * fmaxf(v, 0.f) * W3[lane];   // hn2 element * W3, then reduce
#pragma unroll
    for (int mm = 1; mm < 64; mm <<= 1) r += __shfl_xor(r, mm, 64);
    if (lane == 0) t3[node] = r;
}

// Scalar last layer: out[n] = dinv[n]*(t3[n] + sum t3[src]) + b3
__global__ void k_aggregate3(const int* __restrict__ rowptr, const int* __restrict__ ssrc,
                             const float* __restrict__ t3, const float* __restrict__ dinv,
                             const float* __restrict__ b3, float* __restrict__ out) {
    int n = blockIdx.x * blockDim.x + threadIdx.x;
    if (n >= NN) return;
    int s = rowptr[n], e = rowptr[n + 1];
    float acc = t3[n];
    int i = s;
    for (; i + 4 <= e; i += 4)
        acc += t3[ssrc[i]] + t3[ssrc[i + 1]] + t3[ssrc[i + 2]] + t3[ssrc[i + 3]];
    for (; i < e; ++i) acc += t3[ssrc[i]];
    out[n] = dinv[n] * acc + b3[0];
}

// ---------------------------------------------------------------------------
extern "C" void kernel_launch(void* const* d_in, const int* in_sizes, int n_in,
                              void* d_out, int out_size, void* d_ws, size_t ws_size,
                              hipStream_t stream) {
    const float* x  = (const float*)d_in[0];
    const void*  ei = d_in[1];
    const float* W1 = (const float*)d_in[2];
    const float* b1 = (const float*)d_in[3];
    const float* W2 = (const float*)d_in[4];
    const float* b2 = (const float*)d_in[5];
    const float* W3 = (const float*)d_in[6];
    const float* b3 = (const float*)d_in[7];
    float* out = (float*)d_out;

    char* ws = (char*)d_ws;
    size_t off_b = 0;
    auto take = [&](size_t bytes) -> char* {
        char* p = ws + off_b;
        off_b = (off_b + bytes + 255) & ~(size_t)255;
        return p;
    };
    float*    dinv   = (float*)take((size_t)NN * 4);
    int*      flag   = (int*)take(4);
    int*      bsum   = (int*)take(128 * 4);
    int*      rowptr = (int*)take((size_t)(NN + 1) * 4);
    int*      hist   = (int*)take((size_t)NSC * 4);
    int*      histS  = (int*)take((size_t)NSC * 4);
    unsigned* packed = (unsigned*)take((size_t)NE * 4);
    int*      ssrc   = (int*)take((size_t)NE * 4);
    float2*   xn     = (float2*)take((size_t)NN * 8);
    __half*   hn1    = (__half*)take((size_t)NN * 64 * 2);
    float*    t3     = (float*)take((size_t)NN * 4);

    // --- edge dtype detect ---
    hipMemsetAsync(flag, 0, 4, stream);
    k_detect<<<256, 256, 0, stream>>>((const unsigned int*)ei, flag);

    // --- atomic-free radix partition by dst (coarse buckets of 256 nodes) ---
    k_hist<<<B_P, 256, 0, stream>>>(ei, flag, hist);
    k_gscan1<<<NBLK_H, 256, 0, stream>>>(hist, histS, bsum, NSC);
    k_gscan2<<<1, 128, 0, stream>>>(bsum, NBLK_H);
    k_gscan3<<<(NSC + 255) / 256, 256, 0, stream>>>(histS, bsum, NSC);
    k_part<<<B_P, 256, 0, stream>>>(ei, flag, histS, packed);

    // --- fused per-bucket: count + scan -> rowptr/dinv/xn + place ssrc ---
    k_bucket<<<K_B, 256, 0, stream>>>(histS, packed, x, rowptr, dinv, xn, ssrc);

    const int nblk_agg = (NN + 3) / 4;  // 4 waves (nodes) per block

    // --- layer 1 (lane-parallel 2-wide aggregate + transform, fp16 out) ---
    k_layer1<<<nblk_agg, 256, 0, stream>>>(rowptr, ssrc, xn, dinv, W1, b1, hn1);

    // --- layer 2 + 3a (wide-gather aggregate + GEMM + W3 dot) ---
    k_layer2<<<nblk_agg, 256, 0, stream>>>(rowptr, ssrc, hn1, dinv, W2, b2, W3, t3);

    // --- layer 3b (scalar aggregate) ---
    k_aggregate3<<<(NN + 255) / 256, 256, 0, stream>>>(rowptr, ssrc, t3, dinv, b3, out);
}